// Round 11
// baseline (24247.649 us; speedup 1.0000x reference)
//
#include <hip/hip_runtime.h>
#include <math.h>

#define A_ 64
#define B_ 256
#define D_ 128
#define H_ 512
#define STEPS_ENC 64
#define STEPS_TOT (64 + 16384)   // 64 encoder steps + 256*64 decoder steps
#define NWG 32
#define NTHREADS 1024            // 16 waves, 1 hidden unit each
// dynamic LDS: Whh slice 32768 floats (128KB) + hstage 1024 floats (4KB)
#define WHLDS_N 32768
#define DYN_LDS ((WHLDS_N + 1024) * 4)

// s_getreg immediate: id | offset<<6 | (width-1)<<11 ; HW_REG_XCC_ID = 20
#define XCC_GETREG_IMM (20 | (31 << 11))

// workspace layout (float offsets) — kept identical to prior session for safety
#define OFF_XT    0
#define N_XT      (A_*D_*B_)
#define OFF_HT0   (OFF_XT + N_XT)
#define OFF_HT1   (OFF_HT0 + H_*B_)
#define OFF_CT    (OFF_HT1 + H_*B_)
#define OFF_HTAP  (OFF_CT + H_*B_)        // decoder h taps [256][512]
#define OFF_HB64  (OFF_HTAP + B_*H_)      // tagged h [2][512] u64
#define OFF_CINIT (OFF_HB64 + 4*H_)
#define OFF_ELECT (OFF_CINIT + H_)        // ints: [0..7] per-XCD counters, [8] winner

__device__ __forceinline__ float sigf(float x) {
  return __builtin_amdgcn_rcpf(1.0f + __expf(-x));
}
// tanh(x) = 1 - 2/(e^{2x}+1); exact at saturation
__device__ __forceinline__ float tanhfast(float x) {
  return 1.0f - 2.0f * __builtin_amdgcn_rcpf(__expf(2.0f * x) + 1.0f);
}

// Proven nt+inv protocol (R0-R4, clobber-free form ran correct R7-R9).
__device__ __forceinline__ unsigned long long load_nt(const unsigned long long* p) {
  unsigned long long v;
  asm volatile("global_load_dwordx2 %0, %1, off nt\n\ts_waitcnt vmcnt(0)"
               : "=&v"(v) : "v"(p));
  return v;
}
__device__ __forceinline__ unsigned long long load_inv(const unsigned long long* p) {
  unsigned long long v;
  asm volatile("buffer_inv sc0\n\t"
               "global_load_dwordx2 %0, %1, off nt\n\ts_waitcnt vmcnt(0)"
               : "=&v"(v) : "v"(p));
  return v;
}
__device__ __forceinline__ void store_nt(unsigned long long* p, unsigned long long v) {
  asm volatile("global_store_dwordx2 %0, %1, off nt" :: "v"(p), "v"(v));
}

// DPP add helper (VALU-speed)
template<int CTRL>
__device__ __forceinline__ float dpp_add(float x) {
  int y = __builtin_amdgcn_update_dpp(0, __float_as_int(x), CTRL, 0xF, 0xF, false);
  return x + __int_as_float(y);
}
// full 64-lane all-sum: row ror{8,4,2,1} -> 16-row sums; ds_swizzle xor16
// (within 32-halves) -> half sums; shfl lane^32 -> grand total in ALL lanes.
__device__ __forceinline__ float allsum64(float x, int l) {
  x = dpp_add<0x128>(x);   // row_ror:8
  x = dpp_add<0x124>(x);   // row_ror:4
  x = dpp_add<0x122>(x);   // row_ror:2
  x = dpp_add<0x121>(x);   // row_ror:1
  int y = __builtin_amdgcn_ds_swizzle(__float_as_int(x), 0x401F);  // xor16
  x += __int_as_float(y);
  x += __shfl(x, l ^ 32);  // cross-half
  return x;
}

__device__ __forceinline__ float dot4(float4 a, float4 b) {
  return a.x * b.x + a.y * b.y + a.z * b.z + a.w * b.w;
}

// ---------------------------------------------------------------------------
// init0: seed tagged h (tag 0 = zero-state in parity 1, invalid in parity 0),
// reset election. Encoder h0/c0 are zeros so tag 0 carries h=0.0f.
// ---------------------------------------------------------------------------
__global__ void init0(float* __restrict__ ws) {
  unsigned long long* HB = (unsigned long long*)(ws + OFF_HB64);
  int* EL = (int*)(ws + OFF_ELECT);
  int j = threadIdx.x;                 // 512 threads
  HB[H_ + j] = 0ull;                   // parity 1: tag 0, h = 0.0f
  HB[j]      = 0xFFFFFFFF00000000ull;  // parity 0: invalid
  if (j < 8) EL[j] = 0;
  if (j == 8) EL[8] = -1;              // winner xcd
}

// ---------------------------------------------------------------------------
// R11 = R10 + the bias fix. R10's absmax 1.90 was the bias added in EVERY
// lane's partial BEFORE the 64-lane reduction (counted 64x; prior rounds
// gated it to one lane per group). Fix: add biases AFTER allsum64 — all
// lanes then hold the identical total, so the uniform add is exact.
//
// R10 rationale (unchanged): nine rounds pinned at ~2900cy/step because the
// per-CU 160KB weight slice was re-streamed from the elected XCD's L2 every
// step (VGPR=40/52 proves spill/remat; 5MB/step x 16448 steps / ~20ms =
// 4.1TB/s = ~90% of one XCD's L2 BW — an L2 roofline). Whh now lives in
// LDS (128KB/CU, preloaded once per phase, wave-local). Redundancy-free
// mapping: lane l covers k-slice [8l,8l+8) for ALL 4 gates (32 wh + 8 h
// floats = 160B/lane/step from LDS). Gate sums reduced over the full wave
// (allsum64); activations computed uniformly by all lanes. Handshake
// protocol byte-identical to R2/R7.
// ---------------------------------------------------------------------------
template<int PHASE>
__device__ __forceinline__ void lstm_phase(
    const float* __restrict__ in0,
    const float* __restrict__ Wih, const float* __restrict__ Whh,
    const float* __restrict__ bih, const float* __restrict__ bhh,
    unsigned long long* __restrict__ HB, float* __restrict__ HTAP,
    float* __restrict__ whlds,        // [16][4][512] floats (dynamic LDS)
    float* __restrict__ hstage,       // [2][512] floats   (dynamic LDS)
    int w, int v, int l, float& c)
{
  const int u = (w << 4) + v;        // hidden unit owned by this wave

  // ---- preload this wave's unit weights into LDS (wave-local: wave v both
  // fills and reads only whlds[v]; in-order DS ops + compiler lgkmcnt
  // suffice, no barrier). Lane-contiguous float4 writes: bank-uniform.
  {
    float* wb = whlds + (v << 11);
#pragma unroll
    for (int i = 0; i < 8; ++i) {
      int fl = (l << 2) + (i << 8);              // [0, 2048)
      int gg = fl >> 9, kk = fl & 511;
      *(float4*)&wb[fl] = *(const float4*)&Whh[((gg << 9) + u) * H_ + kk];
    }
  }
  // Wih per lane: gate g, cols [2l, 2l+2)  (8 floats, stays in VGPRs)
  float2 wx0 = *(const float2*)&Wih[((0 << 9) + u) * D_ + (l << 1)];
  float2 wx1 = *(const float2*)&Wih[((1 << 9) + u) * D_ + (l << 1)];
  float2 wx2 = *(const float2*)&Wih[((2 << 9) + u) * D_ + (l << 1)];
  float2 wx3 = *(const float2*)&Wih[((3 << 9) + u) * D_ + (l << 1)];
  // biases (wave-uniform -> scalar loads); added POST-reduction (R11 fix)
  const float b0 = bih[(0 << 9) + u] + bhh[(0 << 9) + u];
  const float b1 = bih[(1 << 9) + u] + bhh[(1 << 9) + u];
  const float b2 = bih[(2 << 9) + u] + bhh[(2 << 9) + u];
  const float b3 = bih[(3 << 9) + u] + bhh[(3 << 9) + u];

  const int pe = (v << 5) + (l & 31);   // polled element (2 lanes per element)
  unsigned wboff = (unsigned)(v << 11); // laundered each iter (anti-hoist)

  const int s0 = (PHASE == 0) ? 0 : STEPS_ENC;
  const int s1 = (PHASE == 0) ? STEPS_ENC : STEPS_TOT;

  for (int s = s0; s < s1; ++s) {
    // x loads — independent of h, issued before the poll to overlap
    const float* xp;
    if (PHASE == 0) {
      xp = in0 + (s * B_ + 255) * D_;                     // x_t = input[t,255,:]
    } else {
      const int sd = s - STEPS_ENC;
      xp = in0 + ((sd & 63) * B_ + (255 - (sd >> 6))) * D_;
    }
    float2 xv = *(const float2*)(xp + (l << 1));

    // poll h_{s-1}: nt loads from the shared L2; inv fallback 1/64 spins
    unsigned long long* slot = &HB[(((s + 1) & 1) << 9) + pe];
    unsigned long long pk;
    int spins = 0;
    for (;;) {
      pk = ((++spins & 63) == 0) ? load_inv(slot) : load_nt(slot);
      if (__all((unsigned)(pk >> 32) == (unsigned)s)) break;
    }
    float* hbuf = hstage + ((s & 1) << 9);
    if (l < 32) hbuf[pe] = __uint_as_float((unsigned)pk);

    // launder the LDS weight base: keeps the 8 wh reads INSIDE the loop
    // (prevents loop-hoist of 32 floats -> spill, the R6 failure mode)
    asm volatile("" : "+v"(wboff));
    const float* wb = whlds + wboff;

    // x contribution while the stage settles (NO bias here — R11 fix)
    float a0 = wx0.x * xv.x + wx0.y * xv.y;
    float a1 = wx1.x * xv.x + wx1.y * xv.y;
    float a2 = wx2.x * xv.x + wx2.y * xv.y;
    float a3 = wx3.x * xv.x + wx3.y * xv.y;

    // weight fragments (wave-local LDS, issued before the barrier)
    const int ko = l << 3;             // this lane's k-slice start
    float4 w0a = *(const float4*)&wb[(0 << 9) + ko];
    float4 w0b = *(const float4*)&wb[(0 << 9) + ko + 4];
    float4 w1a = *(const float4*)&wb[(1 << 9) + ko];
    float4 w1b = *(const float4*)&wb[(1 << 9) + ko + 4];
    float4 w2a = *(const float4*)&wb[(2 << 9) + ko];
    float4 w2b = *(const float4*)&wb[(2 << 9) + ko + 4];
    float4 w3a = *(const float4*)&wb[(3 << 9) + ko];
    float4 w3b = *(const float4*)&wb[(3 << 9) + ko + 4];

    __syncthreads();                      // the ONE barrier per step

    // h slice (8 floats) — read once, used by all 4 gates
    float4 ha = *(const float4*)&hbuf[ko];
    float4 hb = *(const float4*)&hbuf[ko + 4];

    a0 += dot4(w0a, ha) + dot4(w0b, hb);
    a1 += dot4(w1a, ha) + dot4(w1b, hb);
    a2 += dot4(w2a, ha) + dot4(w2b, hb);
    a3 += dot4(w3a, ha) + dot4(w3b, hb);

    // full-wave reductions (4 independent chains, ILP overlaps them),
    // then the wave-uniform bias exactly once (R11 fix)
    a0 = allsum64(a0, l) + b0;
    a1 = allsum64(a1, l) + b1;
    a2 = allsum64(a2, l) + b2;
    a3 = allsum64(a3, l) + b3;

    // all lanes hold all 4 totals -> uniform activation & state update
    float ai = sigf(a0);
    float af = sigf(a1);
    float ag = tanhfast(a2);
    float ao = sigf(a3);
    c = af * c + ai * ag;
    float hn = ao * tanhfast(c);
    if (l == 0) {
      // h taps every 64 steps: s=63 -> q=0 (encoder final), s=127 -> q=1, ...
      if ((s & 63) == 63) {
        int q = s >> 6;
        if (q < 256) HTAP[q * H_ + u] = hn;
      }
      unsigned long long opk =
          ((unsigned long long)(unsigned)(s + 1) << 32) | __float_as_uint(hn);
      store_nt(&HB[((s & 1) << 9) + u], opk);
    }
  }
}

// ---------------------------------------------------------------------------
// fused persistent kernel: 256 WGs launched; the 32 on one elected XCD run
// 64 encoder + 16384 decoder sequential steps; others exit. 132KB dynamic
// LDS (Whh slice + hstage) -> 1 WG/CU.
// ---------------------------------------------------------------------------
__global__ __launch_bounds__(NTHREADS) void fused(
    const float* __restrict__ in0,
    const float* __restrict__ eWih, const float* __restrict__ eWhh,
    const float* __restrict__ ebih, const float* __restrict__ ebhh,
    const float* __restrict__ dWih, const float* __restrict__ dWhh,
    const float* __restrict__ dbih, const float* __restrict__ dbhh,
    float* __restrict__ ws)
{
  unsigned long long* HB = (unsigned long long*)(ws + OFF_HB64);
  float* HTAP = ws + OFF_HTAP;

  extern __shared__ __align__(16) float smem[];
  float* whlds  = smem;                 // [16][4][512]
  float* hstage = smem + WHLDS_N;       // [2][512]
  __shared__ int role;

  const int tid = threadIdx.x;

  // ---- election: first XCD to seat 32 WGs wins; its ranks 0..31 decode ----
  if (tid == 0) {
    unsigned xcc = ((unsigned)__builtin_amdgcn_s_getreg(XCC_GETREG_IMM)) & 7u;
    int* EL = (int*)(ws + OFF_ELECT);
    int r = __hip_atomic_fetch_add(&EL[xcc], 1, __ATOMIC_RELAXED,
                                   __HIP_MEMORY_SCOPE_AGENT);
    int myrole = -1;
    if (r < NWG) {
      if (r == NWG - 1) {
        int exp = -1;
        __hip_atomic_compare_exchange_strong(&EL[8], &exp, (int)xcc,
            __ATOMIC_RELAXED, __ATOMIC_RELAXED, __HIP_MEMORY_SCOPE_AGENT);
      }
      int wx;
      do {
        wx = __hip_atomic_load(&EL[8], __ATOMIC_RELAXED, __HIP_MEMORY_SCOPE_AGENT);
        if (wx == -1) __builtin_amdgcn_s_sleep(2);
      } while (wx == -1);
      if (wx == (int)xcc) myrole = r;
    }
    role = myrole;
  }
  __syncthreads();
  if (role < 0) return;               // uniform per WG
  const int w = role;

  const int v = tid >> 6;             // wave -> hidden unit 16w+v
  const int l = tid & 63;             // lane

  float c = 0.f;                      // encoder starts from h0 = c0 = 0

  lstm_phase<0>(in0, eWih, eWhh, ebih, ebhh, HB, HTAP, whlds, hstage,
                w, v, l, c);
  lstm_phase<1>(in0, dWih, dWhh, dbih, dbhh, HB, HTAP, whlds, hstage,
                w, v, l, c);
}

// ---------------------------------------------------------------------------
// out_proj: outs[255-b] = Htap[255-b] @ lin_W^T + lin_b, broadcast over a.
// ---------------------------------------------------------------------------
__global__ __launch_bounds__(128) void out_proj(
    const float* __restrict__ ws, const float* __restrict__ linW,
    const float* __restrict__ linb, float* __restrict__ out) {
  const float* HTAP = ws + OFF_HTAP;
  __shared__ float hs[H_];
  const int b = blockIdx.x;
  const int i = 255 - b;
  const int d = threadIdx.x;
  *(float4*)&hs[4 * d] = *(const float4*)&HTAP[i * H_ + 4 * d];
  __syncthreads();
  float acc = linb[d];
#pragma unroll 8
  for (int k = 0; k < H_; k += 4) {
    float4 w4 = *(const float4*)&linW[d * H_ + k];
    acc += w4.x * hs[k] + w4.y * hs[k + 1] + w4.z * hs[k + 2] + w4.w * hs[k + 3];
  }
  for (int a = 0; a < A_; ++a)
    out[(a * B_ + b) * D_ + d] = acc;
}

// ---------------------------------------------------------------------------
extern "C" void kernel_launch(void* const* d_in, const int* in_sizes, int n_in,
                              void* d_out, int out_size, void* d_ws, size_t ws_size,
                              hipStream_t stream) {
  const float* in0  = (const float*)d_in[0];
  const float* eWih = (const float*)d_in[1];
  const float* eWhh = (const float*)d_in[2];
  const float* ebih = (const float*)d_in[3];
  const float* ebhh = (const float*)d_in[4];
  const float* dWih = (const float*)d_in[5];
  const float* dWhh = (const float*)d_in[6];
  const float* dbih = (const float*)d_in[7];
  const float* dbhh = (const float*)d_in[8];
  const float* linW = (const float*)d_in[9];
  const float* linb = (const float*)d_in[10];
  float* ws = (float*)d_ws;
  float* out = (float*)d_out;

  // allow >64KB dynamic LDS (immediate API call, safe under graph capture —
  // R6-proven mechanics)
  hipFuncSetAttribute((const void*)fused,
                      hipFuncAttributeMaxDynamicSharedMemorySize, DYN_LDS);

  init0<<<1, 512, 0, stream>>>(ws);
  fused<<<256, NTHREADS, DYN_LDS, stream>>>(in0, eWih, eWhh, ebih, ebhh,
                                            dWih, dWhh, dbih, dbhh, ws);
  out_proj<<<256, 128, 0, stream>>>(ws, linW, linb, out);
}

// Round 12
// 21361.542 us; speedup vs baseline: 1.1351x; 1.1351x over previous
//
#include <hip/hip_runtime.h>
#include <math.h>

#define A_ 64
#define B_ 256
#define D_ 128
#define H_ 512
#define STEPS_ENC 64
#define STEPS_TOT (64 + 16384)   // 64 encoder steps + 256*64 decoder steps
#define NWG 32
#define NTHREADS 1024            // 16 waves, 1 hidden unit each
// dynamic LDS: Whh slice 32768 floats (128KB) + hstage 1024 floats (4KB)
#define WHLDS_N 32768
#define DYN_LDS ((WHLDS_N + 1024) * 4)

// s_getreg immediate: id | offset<<6 | (width-1)<<11 ; HW_REG_XCC_ID = 20
#define XCC_GETREG_IMM (20 | (31 << 11))

// workspace layout (float offsets) — kept identical to prior session for safety
#define OFF_XT    0
#define N_XT      (A_*D_*B_)
#define OFF_HT0   (OFF_XT + N_XT)
#define OFF_HT1   (OFF_HT0 + H_*B_)
#define OFF_CT    (OFF_HT1 + H_*B_)
#define OFF_HTAP  (OFF_CT + H_*B_)        // decoder h taps [256][512]
#define OFF_HB64  (OFF_HTAP + B_*H_)      // tagged h [2][512] u64
#define OFF_CINIT (OFF_HB64 + 4*H_)
#define OFF_ELECT (OFF_CINIT + H_)        // ints: [0..7] per-XCD counters, [8] winner

__device__ __forceinline__ float sigf(float x) {
  return __builtin_amdgcn_rcpf(1.0f + __expf(-x));
}
// tanh(x) = 1 - 2/(e^{2x}+1); exact at saturation
__device__ __forceinline__ float tanhfast(float x) {
  return 1.0f - 2.0f * __builtin_amdgcn_rcpf(__expf(2.0f * x) + 1.0f);
}

// Proven nt+inv protocol (R0-R4, clobber-free form ran correct R7-R11).
__device__ __forceinline__ unsigned long long load_nt(const unsigned long long* p) {
  unsigned long long v;
  asm volatile("global_load_dwordx2 %0, %1, off nt\n\ts_waitcnt vmcnt(0)"
               : "=&v"(v) : "v"(p));
  return v;
}
__device__ __forceinline__ unsigned long long load_inv(const unsigned long long* p) {
  unsigned long long v;
  asm volatile("buffer_inv sc0\n\t"
               "global_load_dwordx2 %0, %1, off nt\n\ts_waitcnt vmcnt(0)"
               : "=&v"(v) : "v"(p));
  return v;
}
__device__ __forceinline__ void store_nt(unsigned long long* p, unsigned long long v) {
  asm volatile("global_store_dwordx2 %0, %1, off nt" :: "v"(p), "v"(v));
}

// DPP add helper (VALU-speed)
template<int CTRL>
__device__ __forceinline__ float dpp_add(float x) {
  int y = __builtin_amdgcn_update_dpp(0, __float_as_int(x), CTRL, 0xF, 0xF, false);
  return x + __int_as_float(y);
}
// full 64-lane all-sum: row ror{8,4,2,1} -> 16-row sums; ds_swizzle xor16
// (within 32-halves) -> half sums; shfl lane^32 -> grand total in ALL lanes.
__device__ __forceinline__ float allsum64(float x, int l) {
  x = dpp_add<0x128>(x);   // row_ror:8
  x = dpp_add<0x124>(x);   // row_ror:4
  x = dpp_add<0x122>(x);   // row_ror:2
  x = dpp_add<0x121>(x);   // row_ror:1
  int y = __builtin_amdgcn_ds_swizzle(__float_as_int(x), 0x401F);  // xor16
  x += __int_as_float(y);
  x += __shfl(x, l ^ 32);  // cross-half
  return x;
}

__device__ __forceinline__ float dot4(float4 a, float4 b) {
  return a.x * b.x + a.y * b.y + a.z * b.z + a.w * b.w;
}

// ---------------------------------------------------------------------------
// init0: seed tagged h (tag 0 = zero-state in parity 1, invalid in parity 0),
// reset election. Encoder h0/c0 are zeros so tag 0 carries h=0.0f.
// ---------------------------------------------------------------------------
__global__ void init0(float* __restrict__ ws) {
  unsigned long long* HB = (unsigned long long*)(ws + OFF_HB64);
  int* EL = (int*)(ws + OFF_ELECT);
  int j = threadIdx.x;                 // 512 threads
  HB[H_ + j] = 0ull;                   // parity 1: tag 0, h = 0.0f
  HB[j]      = 0xFFFFFFFF00000000ull;  // parity 0: invalid
  if (j < 8) EL[j] = 0;
  if (j == 8) EL[8] = -1;              // winner xcd
}

// ---------------------------------------------------------------------------
// R12 = R11 + CONFLICT-FREE LDS LAYOUTS (one variable; everything else
// byte-identical). R11's 3.37e8 SQ_LDS_BANK_CONFLICT (~640cy/CU/step ~ the
// whole 740cy regression vs R2) came from 128B/32B lane strides (16 lanes
// on one 4-bank group). Both layouts are kernel-private, so pure re-index:
//  - weights: lane-major blocks [8][64][4] (block b = gate*2+half); lane l
//    reads float4 at base + b*1024B + l*16B -> canonical conflict-free.
//  - hstage: deinterleaved halves. pos(k): i=k>>3, r=k&7 ->
//    (r<4?0:256) + 4i + (r&3). Lane l reads &h[4l] and &h[256+4l] (16B
//    stride, conflict-free); scattered 1-float stage writes become 2-way
//    worst-case (free, m136).
// Rationale unchanged (R10): break the 5MB/step weight re-stream from the
// elected XCD's L2 (~4.1TB/s = its BW ceiling = the 9-round 2900cy floor).
// This round is the CLEAN test: if step time returns to ~2900cy with
// conflicts gone, the L2-stream theory is falsified and the floor is the
// handshake protocol.
// ---------------------------------------------------------------------------
template<int PHASE>
__device__ __forceinline__ void lstm_phase(
    const float* __restrict__ in0,
    const float* __restrict__ Wih, const float* __restrict__ Whh,
    const float* __restrict__ bih, const float* __restrict__ bhh,
    unsigned long long* __restrict__ HB, float* __restrict__ HTAP,
    float* __restrict__ whlds,        // [16][8][64][4] floats (dynamic LDS)
    float* __restrict__ hstage,       // [2][512] floats    (dynamic LDS)
    int w, int v, int l, float& c)
{
  const int u = (w << 4) + v;        // hidden unit owned by this wave

  // ---- preload this wave's unit weights into LDS, lane-major blocks.
  // wave-local (wave v fills and reads only whlds[v]); in-order DS ops +
  // compiler lgkmcnt suffice, no barrier. Writes: 16B lane stride = clean.
  {
    float* wb = whlds + (v << 11);
#pragma unroll
    for (int b = 0; b < 8; ++b) {
      int g = b >> 1, half = b & 1;
      float4 src = *(const float4*)
          &Whh[((g << 9) + u) * H_ + (l << 3) + (half << 2)];
      *(float4*)&wb[(b << 8) + (l << 2)] = src;
    }
  }
  // Wih per lane: gate g, cols [2l, 2l+2)  (8 floats, stays in VGPRs)
  float2 wx0 = *(const float2*)&Wih[((0 << 9) + u) * D_ + (l << 1)];
  float2 wx1 = *(const float2*)&Wih[((1 << 9) + u) * D_ + (l << 1)];
  float2 wx2 = *(const float2*)&Wih[((2 << 9) + u) * D_ + (l << 1)];
  float2 wx3 = *(const float2*)&Wih[((3 << 9) + u) * D_ + (l << 1)];
  // biases (wave-uniform -> scalar loads); added POST-reduction (R11 fix)
  const float b0 = bih[(0 << 9) + u] + bhh[(0 << 9) + u];
  const float b1 = bih[(1 << 9) + u] + bhh[(1 << 9) + u];
  const float b2 = bih[(2 << 9) + u] + bhh[(2 << 9) + u];
  const float b3 = bih[(3 << 9) + u] + bhh[(3 << 9) + u];

  const int pe = (v << 5) + (l & 31);   // polled element (2 lanes per element)
  // deinterleaved stage position for pe: i=pe>>3, r=pe&7
  const int hpos = ((pe & 4) << 6) + ((pe >> 3) << 2) + (pe & 3);
  unsigned wboff = (unsigned)(v << 11); // laundered each iter (anti-hoist)

  const int s0 = (PHASE == 0) ? 0 : STEPS_ENC;
  const int s1 = (PHASE == 0) ? STEPS_ENC : STEPS_TOT;

  for (int s = s0; s < s1; ++s) {
    // x loads — independent of h, issued before the poll to overlap
    const float* xp;
    if (PHASE == 0) {
      xp = in0 + (s * B_ + 255) * D_;                     // x_t = input[t,255,:]
    } else {
      const int sd = s - STEPS_ENC;
      xp = in0 + ((sd & 63) * B_ + (255 - (sd >> 6))) * D_;
    }
    float2 xv = *(const float2*)(xp + (l << 1));

    // poll h_{s-1}: nt loads from the shared L2; inv fallback 1/64 spins
    unsigned long long* slot = &HB[(((s + 1) & 1) << 9) + pe];
    unsigned long long pk;
    int spins = 0;
    for (;;) {
      pk = ((++spins & 63) == 0) ? load_inv(slot) : load_nt(slot);
      if (__all((unsigned)(pk >> 32) == (unsigned)s)) break;
    }
    float* hbuf = hstage + ((s & 1) << 9);
    if (l < 32) hbuf[hpos] = __uint_as_float((unsigned)pk);

    // launder the LDS weight base: keeps the 8 wh reads INSIDE the loop
    // (prevents loop-hoist of 32 floats -> spill, the R6 failure mode)
    asm volatile("" : "+v"(wboff));
    const float* wb = whlds + wboff;

    // x contribution while the stage settles (bias added post-reduction)
    float a0 = wx0.x * xv.x + wx0.y * xv.y;
    float a1 = wx1.x * xv.x + wx1.y * xv.y;
    float a2 = wx2.x * xv.x + wx2.y * xv.y;
    float a3 = wx3.x * xv.x + wx3.y * xv.y;

    // weight fragments (wave-local LDS, lane-major blocks: conflict-free;
    // issued before the barrier so they overlap the other waves' polls)
    const int lo = l << 2;
    float4 w0a = *(const float4*)&wb[(0 << 8) + lo];
    float4 w0b = *(const float4*)&wb[(1 << 8) + lo];
    float4 w1a = *(const float4*)&wb[(2 << 8) + lo];
    float4 w1b = *(const float4*)&wb[(3 << 8) + lo];
    float4 w2a = *(const float4*)&wb[(4 << 8) + lo];
    float4 w2b = *(const float4*)&wb[(5 << 8) + lo];
    float4 w3a = *(const float4*)&wb[(6 << 8) + lo];
    float4 w3b = *(const float4*)&wb[(7 << 8) + lo];

    __syncthreads();                      // the ONE barrier per step

    // h slice (8 floats) — deinterleaved reads, 16B lane stride (clean)
    float4 ha = *(const float4*)&hbuf[lo];
    float4 hb = *(const float4*)&hbuf[256 + lo];

    a0 += dot4(w0a, ha) + dot4(w0b, hb);
    a1 += dot4(w1a, ha) + dot4(w1b, hb);
    a2 += dot4(w2a, ha) + dot4(w2b, hb);
    a3 += dot4(w3a, ha) + dot4(w3b, hb);

    // full-wave reductions (4 independent chains, ILP overlaps them),
    // then the wave-uniform bias exactly once
    a0 = allsum64(a0, l) + b0;
    a1 = allsum64(a1, l) + b1;
    a2 = allsum64(a2, l) + b2;
    a3 = allsum64(a3, l) + b3;

    // all lanes hold all 4 totals -> uniform activation & state update
    float ai = sigf(a0);
    float af = sigf(a1);
    float ag = tanhfast(a2);
    float ao = sigf(a3);
    c = af * c + ai * ag;
    float hn = ao * tanhfast(c);
    if (l == 0) {
      // h taps every 64 steps: s=63 -> q=0 (encoder final), s=127 -> q=1, ...
      if ((s & 63) == 63) {
        int q = s >> 6;
        if (q < 256) HTAP[q * H_ + u] = hn;
      }
      unsigned long long opk =
          ((unsigned long long)(unsigned)(s + 1) << 32) | __float_as_uint(hn);
      store_nt(&HB[((s & 1) << 9) + u], opk);
    }
  }
}

// ---------------------------------------------------------------------------
// fused persistent kernel: 256 WGs launched; the 32 on one elected XCD run
// 64 encoder + 16384 decoder sequential steps; others exit. 132KB dynamic
// LDS (Whh slice + hstage) -> 1 WG/CU.
// ---------------------------------------------------------------------------
__global__ __launch_bounds__(NTHREADS) void fused(
    const float* __restrict__ in0,
    const float* __restrict__ eWih, const float* __restrict__ eWhh,
    const float* __restrict__ ebih, const float* __restrict__ ebhh,
    const float* __restrict__ dWih, const float* __restrict__ dWhh,
    const float* __restrict__ dbih, const float* __restrict__ dbhh,
    float* __restrict__ ws)
{
  unsigned long long* HB = (unsigned long long*)(ws + OFF_HB64);
  float* HTAP = ws + OFF_HTAP;

  extern __shared__ __align__(16) float smem[];
  float* whlds  = smem;                 // [16][8][64][4]
  float* hstage = smem + WHLDS_N;       // [2][512] deinterleaved
  __shared__ int role;

  const int tid = threadIdx.x;

  // ---- election: first XCD to seat 32 WGs wins; its ranks 0..31 decode ----
  if (tid == 0) {
    unsigned xcc = ((unsigned)__builtin_amdgcn_s_getreg(XCC_GETREG_IMM)) & 7u;
    int* EL = (int*)(ws + OFF_ELECT);
    int r = __hip_atomic_fetch_add(&EL[xcc], 1, __ATOMIC_RELAXED,
                                   __HIP_MEMORY_SCOPE_AGENT);
    int myrole = -1;
    if (r < NWG) {
      if (r == NWG - 1) {
        int exp = -1;
        __hip_atomic_compare_exchange_strong(&EL[8], &exp, (int)xcc,
            __ATOMIC_RELAXED, __ATOMIC_RELAXED, __HIP_MEMORY_SCOPE_AGENT);
      }
      int wx;
      do {
        wx = __hip_atomic_load(&EL[8], __ATOMIC_RELAXED, __HIP_MEMORY_SCOPE_AGENT);
        if (wx == -1) __builtin_amdgcn_s_sleep(2);
      } while (wx == -1);
      if (wx == (int)xcc) myrole = r;
    }
    role = myrole;
  }
  __syncthreads();
  if (role < 0) return;               // uniform per WG
  const int w = role;

  const int v = tid >> 6;             // wave -> hidden unit 16w+v
  const int l = tid & 63;             // lane

  float c = 0.f;                      // encoder starts from h0 = c0 = 0

  lstm_phase<0>(in0, eWih, eWhh, ebih, ebhh, HB, HTAP, whlds, hstage,
                w, v, l, c);
  lstm_phase<1>(in0, dWih, dWhh, dbih, dbhh, HB, HTAP, whlds, hstage,
                w, v, l, c);
}

// ---------------------------------------------------------------------------
// out_proj: outs[255-b] = Htap[255-b] @ lin_W^T + lin_b, broadcast over a.
// ---------------------------------------------------------------------------
__global__ __launch_bounds__(128) void out_proj(
    const float* __restrict__ ws, const float* __restrict__ linW,
    const float* __restrict__ linb, float* __restrict__ out) {
  const float* HTAP = ws + OFF_HTAP;
  __shared__ float hs[H_];
  const int b = blockIdx.x;
  const int i = 255 - b;
  const int d = threadIdx.x;
  *(float4*)&hs[4 * d] = *(const float4*)&HTAP[i * H_ + 4 * d];
  __syncthreads();
  float acc = linb[d];
#pragma unroll 8
  for (int k = 0; k < H_; k += 4) {
    float4 w4 = *(const float4*)&linW[d * H_ + k];
    acc += w4.x * hs[k] + w4.y * hs[k + 1] + w4.z * hs[k + 2] + w4.w * hs[k + 3];
  }
  for (int a = 0; a < A_; ++a)
    out[(a * B_ + b) * D_ + d] = acc;
}

// ---------------------------------------------------------------------------
extern "C" void kernel_launch(void* const* d_in, const int* in_sizes, int n_in,
                              void* d_out, int out_size, void* d_ws, size_t ws_size,
                              hipStream_t stream) {
  const float* in0  = (const float*)d_in[0];
  const float* eWih = (const float*)d_in[1];
  const float* eWhh = (const float*)d_in[2];
  const float* ebih = (const float*)d_in[3];
  const float* ebhh = (const float*)d_in[4];
  const float* dWih = (const float*)d_in[5];
  const float* dWhh = (const float*)d_in[6];
  const float* dbih = (const float*)d_in[7];
  const float* dbhh = (const float*)d_in[8];
  const float* linW = (const float*)d_in[9];
  const float* linb = (const float*)d_in[10];
  float* ws = (float*)d_ws;
  float* out = (float*)d_out;

  // allow >64KB dynamic LDS (immediate API call, safe under graph capture —
  // R6-proven mechanics)
  hipFuncSetAttribute((const void*)fused,
                      hipFuncAttributeMaxDynamicSharedMemorySize, DYN_LDS);

  init0<<<1, 512, 0, stream>>>(ws);
  fused<<<256, NTHREADS, DYN_LDS, stream>>>(in0, eWih, eWhh, ebih, ebhh,
                                            dWih, dWhh, dbih, dbhh, ws);
  out_proj<<<256, 128, 0, stream>>>(ws, linW, linb, out);
}

// Round 13
// 18049.321 us; speedup vs baseline: 1.3434x; 1.1835x over previous
//
#include <hip/hip_runtime.h>
#include <math.h>

#define A_ 64
#define B_ 256
#define D_ 128
#define H_ 512
#define STEPS_ENC 64
#define STEPS_TOT (64 + 16384)   // 64 encoder steps + 256*64 decoder steps
#define NWG 32
#define NTHREADS 1024            // 16 waves, 1 hidden unit each (R2-proven)

// s_getreg immediate: id | offset<<6 | (width-1)<<11 ; HW_REG_XCC_ID = 20
#define XCC_GETREG_IMM (20 | (31 << 11))

typedef float f4v __attribute__((ext_vector_type(4)));

// workspace layout (float offsets) — kept identical to prior session for safety
#define OFF_XT    0
#define N_XT      (A_*D_*B_)
#define OFF_HT0   (OFF_XT + N_XT)
#define OFF_HT1   (OFF_HT0 + H_*B_)
#define OFF_CT    (OFF_HT1 + H_*B_)
#define OFF_HTAP  (OFF_CT + H_*B_)        // decoder h taps [256][512]
#define OFF_HB64  (OFF_HTAP + B_*H_)      // tagged h [2][512] u64
#define OFF_CINIT (OFF_HB64 + 4*H_)
#define OFF_ELECT (OFF_CINIT + H_)        // ints: [0..7] per-XCD counters, [8] winner

// tanh(x) = 1 - 2/(e^{2x}+1); exact at saturation
__device__ __forceinline__ float tanhfast(float x) {
  return 1.0f - 2.0f * __builtin_amdgcn_rcpf(__expf(2.0f * x) + 1.0f);
}

// Proven nt+inv protocol (R0-R4; clobber-free form ran correct R7-R12).
__device__ __forceinline__ unsigned long long load_nt(const unsigned long long* p) {
  unsigned long long v;
  asm volatile("global_load_dwordx2 %0, %1, off nt\n\ts_waitcnt vmcnt(0)"
               : "=&v"(v) : "v"(p));
  return v;
}
__device__ __forceinline__ unsigned long long load_inv(const unsigned long long* p) {
  unsigned long long v;
  asm volatile("buffer_inv sc0\n\t"
               "global_load_dwordx2 %0, %1, off nt\n\ts_waitcnt vmcnt(0)"
               : "=&v"(v) : "v"(p));
  return v;
}
__device__ __forceinline__ void store_nt(unsigned long long* p, unsigned long long v) {
  asm volatile("global_store_dwordx2 %0, %1, off nt" :: "v"(p), "v"(v));
}

// DPP rotate-reduce within each 16-lane row: after ror{8,4,2,1} add chain,
// EVERY lane of the row holds the 16-lane sum. VALU-speed (no LDS).
template<int CTRL>
__device__ __forceinline__ float dpp_ror_add(float x) {
  int y = __builtin_amdgcn_update_dpp(0, __float_as_int(x), CTRL, 0xF, 0xF, false);
  return x + __int_as_float(y);
}
__device__ __forceinline__ float row_allsum16(float x) {
  x = dpp_ror_add<0x128>(x);   // row_ror:8
  x = dpp_ror_add<0x124>(x);   // row_ror:4
  x = dpp_ror_add<0x122>(x);   // row_ror:2
  x = dpp_ror_add<0x121>(x);   // row_ror:1
  return x;
}

// padded hstage: chunk c = k>>5 stored at 36c + (k&31) (R2-proven layout).
#define HSP 36
#define HS_N (16 * HSP)   // 576 floats per parity buffer

// ---------------------------------------------------------------------------
// init0: seed tagged h (tag 0 = zero-state in parity 1, invalid in parity 0),
// reset election. Encoder h0/c0 are zeros so tag 0 carries h=0.0f.
// ---------------------------------------------------------------------------
__global__ void init0(float* __restrict__ ws) {
  unsigned long long* HB = (unsigned long long*)(ws + OFF_HB64);
  int* EL = (int*)(ws + OFF_ELECT);
  int j = threadIdx.x;                 // 512 threads
  HB[H_ + j] = 0ull;                   // parity 1: tag 0, h = 0.0f
  HB[j]      = 0xFFFFFFFF00000000ull;  // parity 0: invalid
  if (j < 8) EL[j] = 0;
  if (j == 8) EL[8] = -1;              // winner xcd
}

// ---------------------------------------------------------------------------
// One LSTM recurrence phase — R7 skeleton (best measured: 18.30ms),
// R13 delta: PACKED MATH ONLY. R12's clean experiment falsified the L2
// weight-stream theory (LDS-resident weights, conflicts fixed: no faster),
// so the weight reloads here are overlapped/free and the reducible term is
// VALU ISSUE COUNT. The x-partial (8 scalar fma -> 4 v_pk_fma_f32) and the
// h-dot (32 scalar fma -> 16 v_pk_fma_f32) are rewritten on f4v vectors;
// one horizontal fold feeds the proven row_allsum16 + shfl + activation
// tail. Protocol, layout, indices byte-identical to R7.
// ---------------------------------------------------------------------------
template<int PHASE>
__device__ __forceinline__ void lstm_phase(
    const float* __restrict__ in0,
    const float* __restrict__ Wih, const float* __restrict__ Whh,
    const float* __restrict__ bih, const float* __restrict__ bhh,
    unsigned long long* __restrict__ HB, float* __restrict__ HTAP,
    float* hstage,                    // [2][HS_N]
    int w, int v, int l, float& c,
    float actA, float actB, float actC)
{
  const int g = l >> 4;              // gate: 0=i 1=f 2=g~ 3=o
  const int j = l & 15;              // reduction lane / k-slice
  const int u = (w << 4) + v;        // hidden unit owned by this wave
  const int R = (g << 9) + u;        // global gate row

  f4v wh[8];
#pragma unroll
  for (int k = 0; k < 8; ++k)
    wh[k] = *(const f4v*)&Whh[R * H_ + (j << 5) + (k << 2)];
  f4v wx0 = *(const f4v*)&Wih[R * D_ + (j << 3)];
  f4v wx1 = *(const f4v*)&Wih[R * D_ + (j << 3) + 4];
  const float bias = (j == 0) ? (bih[R] + bhh[R]) : 0.f;  // counted once/row

  const int pe = (v << 5) + (l & 31);   // polled element (2 lanes per element)

  const int s0 = (PHASE == 0) ? 0 : STEPS_ENC;
  const int s1 = (PHASE == 0) ? STEPS_ENC : STEPS_TOT;

  for (int s = s0; s < s1; ++s) {
    // x loads — independent of h, issued before the poll to overlap
    const float* xp;
    if (PHASE == 0) {
      xp = in0 + (s * B_ + 255) * D_;                     // x_t = input[t,255,:]
    } else {
      const int sd = s - STEPS_ENC;
      xp = in0 + ((sd & 63) * B_ + (255 - (sd >> 6))) * D_;
    }
    f4v x0 = *(const f4v*)(xp + (j << 3));
    f4v x1 = *(const f4v*)(xp + (j << 3) + 4);

    // poll h_{s-1}: nt loads from the shared L2; inv fallback 1/64 spins
    unsigned long long* slot = &HB[(((s + 1) & 1) << 9) + pe];
    unsigned long long pk;
    int spins = 0;
    for (;;) {
      pk = ((++spins & 63) == 0) ? load_inv(slot) : load_nt(slot);
      if (__all((unsigned)(pk >> 32) == (unsigned)s)) break;
    }
    float* hbuf = hstage + (s & 1) * HS_N;
    if (l < 32) hbuf[(v * HSP) + (l & 31)] = __uint_as_float((unsigned)pk);

    // x contribution (packed) while the stage settles
    f4v acc4a = wx0 * x0;
    f4v acc4b = wx1 * x1;

    __syncthreads();                      // the ONE barrier per step

    // full-H dot: 16 v_pk_fma_f32 over two accumulators (halved dep chain)
    const f4v* hp = (const f4v*)&hbuf[j * HSP];
#pragma unroll
    for (int k = 0; k < 8; k += 2) {
      acc4a += wh[k]     * hp[k];
      acc4b += wh[k + 1] * hp[k + 1];
    }
    f4v acc4 = acc4a + acc4b;
    float accs = bias + ((acc4.x + acc4.y) + (acc4.z + acc4.w));

    // 16-lane rotate-reduce: every lane of group g now holds gate-g sum
    float a = row_allsum16(accs);
    // unified activation: i,f,o -> sigmoid; g~ -> tanh (per-lane constants)
    a = fmaf(actA, __builtin_amdgcn_rcpf(__expf(actB * a) + 1.0f), actC);
    // gather the 4 gates (group-uniform values -> broadcast)
    float ai = __shfl(a, 0);
    float af = __shfl(a, 16);
    float ag = __shfl(a, 32);
    float ao = __shfl(a, 48);
    c = af * c + ai * ag;                 // uniform across the wave
    float hn = ao * tanhfast(c);
    if (l == 0) {
      // h taps every 64 steps: s=63 -> q=0 (encoder final), s=127 -> q=1, ...
      if ((s & 63) == 63) {
        int q = s >> 6;
        if (q < 256) HTAP[q * H_ + u] = hn;
      }
      unsigned long long opk =
          ((unsigned long long)(unsigned)(s + 1) << 32) | __float_as_uint(hn);
      store_nt(&HB[((s & 1) << 9) + u], opk);
    }
  }
}

// ---------------------------------------------------------------------------
// fused persistent kernel: 256 WGs launched; the 32 on one elected XCD run
// 64 encoder + 16384 decoder sequential steps; others exit.
// ---------------------------------------------------------------------------
__global__ __launch_bounds__(NTHREADS, 1) void fused(
    const float* __restrict__ in0,
    const float* __restrict__ eWih, const float* __restrict__ eWhh,
    const float* __restrict__ ebih, const float* __restrict__ ebhh,
    const float* __restrict__ dWih, const float* __restrict__ dWhh,
    const float* __restrict__ dbih, const float* __restrict__ dbhh,
    float* __restrict__ ws)
{
  unsigned long long* HB = (unsigned long long*)(ws + OFF_HB64);
  float* HTAP = ws + OFF_HTAP;

  __shared__ __align__(16) float hstage[2][HS_N];  // parity double-buffered
  __shared__ int role;

  const int tid = threadIdx.x;

  // ---- election: first XCD to seat 32 WGs wins; its ranks 0..31 decode ----
  if (tid == 0) {
    unsigned xcc = ((unsigned)__builtin_amdgcn_s_getreg(XCC_GETREG_IMM)) & 7u;
    int* EL = (int*)(ws + OFF_ELECT);
    int r = __hip_atomic_fetch_add(&EL[xcc], 1, __ATOMIC_RELAXED,
                                   __HIP_MEMORY_SCOPE_AGENT);
    int myrole = -1;
    if (r < NWG) {
      if (r == NWG - 1) {
        int exp = -1;
        __hip_atomic_compare_exchange_strong(&EL[8], &exp, (int)xcc,
            __ATOMIC_RELAXED, __ATOMIC_RELAXED, __HIP_MEMORY_SCOPE_AGENT);
      }
      int wx;
      do {
        wx = __hip_atomic_load(&EL[8], __ATOMIC_RELAXED, __HIP_MEMORY_SCOPE_AGENT);
        if (wx == -1) __builtin_amdgcn_s_sleep(2);
      } while (wx == -1);
      if (wx == (int)xcc) myrole = r;
    }
    role = myrole;
  }
  __syncthreads();
  if (role < 0) return;               // uniform per WG
  const int w = role;

  const int v = tid >> 6;             // wave -> hidden unit 16w+v
  const int l = tid & 63;             // lane

  // per-lane unified-activation constants by gate (l>>4): 0=i,1=f,2=g,3=o
  const int gate = l >> 4;
  const float actA = (gate == 2) ? -2.0f :  1.0f;
  const float actB = (gate == 2) ?  2.0f : -1.0f;
  const float actC = (gate == 2) ?  1.0f :  0.0f;

  float c = 0.f;                      // encoder starts from h0 = c0 = 0

  lstm_phase<0>(in0, eWih, eWhh, ebih, ebhh, HB, HTAP, &hstage[0][0],
                w, v, l, c, actA, actB, actC);
  lstm_phase<1>(in0, dWih, dWhh, dbih, dbhh, HB, HTAP, &hstage[0][0],
                w, v, l, c, actA, actB, actC);
}

// ---------------------------------------------------------------------------
// out_proj: outs[255-b] = Htap[255-b] @ lin_W^T + lin_b, broadcast over a.
// ---------------------------------------------------------------------------
__global__ __launch_bounds__(128) void out_proj(
    const float* __restrict__ ws, const float* __restrict__ linW,
    const float* __restrict__ linb, float* __restrict__ out) {
  const float* HTAP = ws + OFF_HTAP;
  __shared__ float hs[H_];
  const int b = blockIdx.x;
  const int i = 255 - b;
  const int d = threadIdx.x;
  *(float4*)&hs[4 * d] = *(const float4*)&HTAP[i * H_ + 4 * d];
  __syncthreads();
  float acc = linb[d];
#pragma unroll 8
  for (int k = 0; k < H_; k += 4) {
    float4 w4 = *(const float4*)&linW[d * H_ + k];
    acc += w4.x * hs[k] + w4.y * hs[k + 1] + w4.z * hs[k + 2] + w4.w * hs[k + 3];
  }
  for (int a = 0; a < A_; ++a)
    out[(a * B_ + b) * D_ + d] = acc;
}

// ---------------------------------------------------------------------------
extern "C" void kernel_launch(void* const* d_in, const int* in_sizes, int n_in,
                              void* d_out, int out_size, void* d_ws, size_t ws_size,
                              hipStream_t stream) {
  const float* in0  = (const float*)d_in[0];
  const float* eWih = (const float*)d_in[1];
  const float* eWhh = (const float*)d_in[2];
  const float* ebih = (const float*)d_in[3];
  const float* ebhh = (const float*)d_in[4];
  const float* dWih = (const float*)d_in[5];
  const float* dWhh = (const float*)d_in[6];
  const float* dbih = (const float*)d_in[7];
  const float* dbhh = (const float*)d_in[8];
  const float* linW = (const float*)d_in[9];
  const float* linb = (const float*)d_in[10];
  float* ws = (float*)d_ws;
  float* out = (float*)d_out;

  init0<<<1, 512, 0, stream>>>(ws);
  fused<<<256, NTHREADS, 0, stream>>>(in0, eWih, eWhh, ebih, ebhh,
                                      dWih, dWhh, dbih, dbhh, ws);
  out_proj<<<256, 128, 0, stream>>>(ws, linW, linb, out);
}